// Round 7
// baseline (512.919 us; speedup 1.0000x reference)
//
#include <hip/hip_runtime.h>

typedef __bf16 bf16_t;
typedef bf16_t bf16x8 __attribute__((ext_vector_type(8)));
typedef float  floatx4 __attribute__((ext_vector_type(4)));
typedef unsigned int uint;

constexpr int Mdim = 2048;
constexpr int Kdim = 4096;
constexpr int Ndim = 11008;
constexpr int NPK  = Ndim / 8;     // 1376 packed words per k-row
constexpr int SQ   = 68;           // qbuf stride (words)
// fused-fallback tile params
constexpr int BM = 128, BN = 128, BK = 64;
constexpr int SA = 72, SB = 72;

#define GLOAD_LDS16(g, l) \
    __builtin_amdgcn_global_load_lds((const __attribute__((address_space(1))) void*)(g), \
                                     (__attribute__((address_space(3))) void*)(l), 16, 0, 0)
#define MFMA(a, b, c) __builtin_amdgcn_mfma_f32_16x16x32_bf16((a), (b), (c), 0, 0, 0)
#define BAR()    __builtin_amdgcn_s_barrier()
#define LGKM0()  asm volatile("s_waitcnt lgkmcnt(0)" ::: "memory")
#define VMCNT6() asm volatile("s_waitcnt vmcnt(6)" ::: "memory")
#define VMCNT0() asm volatile("s_waitcnt vmcnt(0)" ::: "memory")
#define PRIO1()  __builtin_amdgcn_s_setprio(1)
#define PRIO0()  __builtin_amdgcn_s_setprio(0)

__global__ void xcast_kernel(const float* __restrict__ x, bf16_t* __restrict__ xb)
{
    const int i = (blockIdx.x * 256 + threadIdx.x) * 8;
    const float4 a = *(const float4*)(x + i);
    const float4 b = *(const float4*)(x + i + 4);
    bf16x8 v;
    v[0] = (bf16_t)a.x; v[1] = (bf16_t)a.y; v[2] = (bf16_t)a.z; v[3] = (bf16_t)a.w;
    v[4] = (bf16_t)b.x; v[5] = (bf16_t)b.y; v[6] = (bf16_t)b.z; v[7] = (bf16_t)b.w;
    *(bf16x8*)(xb + i) = v;
}

// ---------------------------------------------------------------------------
// Fused prep: W dequant (qweight [k][c] -> wt [n][k] bf16) + xcast slice.
// ---------------------------------------------------------------------------
__global__ __launch_bounds__(256, 4)
void wprep_kernel(const uint* __restrict__ qweight, const uint* __restrict__ qzeros,
                  const float* __restrict__ scales, bf16_t* __restrict__ wt,
                  const float* __restrict__ x, bf16_t* __restrict__ xb)
{
    __shared__ uint qbuf[16 * SQ];
    const int t    = threadIdx.x;
    const int n0   = blockIdx.x * 128;
    const int k0   = blockIdx.y * 64;
    const int c0   = n0 >> 3;
    const int g    = k0 >> 7;
    const int flat = blockIdx.y * 86 + blockIdx.x;

    // --- xcast slice: issue load early ---
    const int xi = flat * 256 + t;                 // vec8 index
    const bool xdo = xi < (Mdim * Kdim) / 8;
    float4 xa, xb4;
    if (xdo) {
        xa  = *(const float4*)(x + xi * 8);
        xb4 = *(const float4*)(x + xi * 8 + 4);
    }

    // --- wdeq stage: 64k x 16c packed words, transposed to qbuf[c][k] ---
    const int qk  = t >> 2;
    const int qc4 = (t & 3) * 4;
    const uint4 w4 = *(const uint4*)(qweight + (size_t)(k0 + qk) * NPK + c0 + qc4);
    qbuf[(qc4 + 0) * SQ + qk] = w4.x;
    qbuf[(qc4 + 1) * SQ + qk] = w4.y;
    qbuf[(qc4 + 2) * SQ + qk] = w4.z;
    qbuf[(qc4 + 3) * SQ + qk] = w4.w;
    __syncthreads();

    const int kcol = t & 7;            // k-word block
    const int nr   = t >> 3;           // 0..31
    const int jsh  = (nr & 7) * 4;     // invariant across j (row += 32)
#pragma unroll
    for (int j = 0; j < 4; ++j) {
        const int row = nr + j * 32;          // 0..127
        const int cc  = row >> 3;             // 0..15
        const uint  zw = qzeros[(size_t)g * NPK + c0 + cc];
        const float s  = scales[(size_t)g * Ndim + n0 + row];
        const float zs = (float)((zw >> jsh) & 15u) * s;
        const uint* qrow = &qbuf[cc * SQ + kcol * 8];
        const uint4 qa = *(const uint4*)(qrow);
        const uint4 qb = *(const uint4*)(qrow + 4);
        bf16x8 v;
        v[0] = (bf16_t)((float)((qa.x >> jsh) & 15u) * s - zs);
        v[1] = (bf16_t)((float)((qa.y >> jsh) & 15u) * s - zs);
        v[2] = (bf16_t)((float)((qa.z >> jsh) & 15u) * s - zs);
        v[3] = (bf16_t)((float)((qa.w >> jsh) & 15u) * s - zs);
        v[4] = (bf16_t)((float)((qb.x >> jsh) & 15u) * s - zs);
        v[5] = (bf16_t)((float)((qb.y >> jsh) & 15u) * s - zs);
        v[6] = (bf16_t)((float)((qb.z >> jsh) & 15u) * s - zs);
        v[7] = (bf16_t)((float)((qb.w >> jsh) & 15u) * s - zs);
        *(bf16x8*)(wt + (size_t)(n0 + row) * Kdim + k0 + kcol * 8) = v;
    }

    // --- xcast store ---
    if (xdo) {
        bf16x8 v;
        v[0] = (bf16_t)xa.x; v[1] = (bf16_t)xa.y; v[2] = (bf16_t)xa.z; v[3] = (bf16_t)xa.w;
        v[4] = (bf16_t)xb4.x; v[5] = (bf16_t)xb4.y; v[6] = (bf16_t)xb4.z; v[7] = (bf16_t)xb4.w;
        *(bf16x8*)(xb + xi * 8) = v;
    }
}

// ---------------------------------------------------------------------------
// Phased bf16 GEMM, K-SPLIT waves, 3-deep pipeline.
// BM=256, BN=128, BK=64. 512 threads = 8 waves as 2M x 2N x 2K.
// ROUND-4 phase skeleton (2 phases/tile, 4 BARs/tile, stages split across
// phases, setprio around MFMA) + depth change ONLY:
//   3 LDS bufs (As 96K + Bs 48K = 144 KiB), stage tile t+2 during tile t,
//   ONE vmcnt(6) per tile at end of phase B -> in-flight never drains
//   below 6 loads (1 full tile); issue-to-wait distance 2-3 phases.
// Ledger:
//   RAW tile t reads @phA(t): protected by VMCNT6@phB(t-1) (outstanding
//     then = t+1's 6) + BAR.  Prologue VMCNT6 covers t=0.
//   WAR stage into buf (t+2)%3 == (t-1)%3: all waves' t-1 reads completed
//     (LGKM0 before MFMA) before they cross phB(t-1)'s closing BAR; stages
//     are issued after that BAR.
//   Tail: t=62,63 stage garbage (T&63) into bufs 1,2 -> explicit
//     VMCNT0+BAR before epilogue (exchange reuses As bufs 0-1).
// ---------------------------------------------------------------------------
__global__ __launch_bounds__(512, 2)
void gemm8_kernel(const bf16_t* __restrict__ xb, const bf16_t* __restrict__ wt,
                  const float* __restrict__ bias, float* __restrict__ out)
{
    __shared__ bf16_t As[3 * 16384];   // 96 KiB  [buf][h][128][64]
    __shared__ bf16_t Bs[3 * 8192];    // 48 KiB  [buf][128][64]

    const int t    = threadIdx.x;
    const int w    = t >> 6;
    const int lane = t & 63;
    const int quad = lane >> 4;
    const int l16  = lane & 15;
    const int wm   = w >> 2;           // 0..1  (m half)
    const int wn   = (w >> 1) & 1;     // 0..1  (n half)
    const int wk   = w & 1;            // 0..1  (k slice)
    const int w64  = w * 64;

    // T1: XCD-aware remap (688 = 8*86, bijective).
    const int flat = blockIdx.y * 86 + blockIdx.x;
    const int nf   = (flat & 7) * 86 + (flat >> 3);
    const int m0   = (nf / 86) * 256;
    const int n0   = (nf % 86) * 128;

    auto stageA = [&](int b, int T, int h) {
        const int Tk = (T & 63) * 64;
#pragma unroll
        for (int l = 0; l < 2; ++l) {
            const int idx = l * 512 + w64 + lane;
            const int r   = idx >> 3;
            const int bc  = (idx & 7) ^ (r & 7);
            GLOAD_LDS16(xb + (size_t)(m0 + h * 128 + r) * Kdim + Tk + bc * 8,
                        As + (b * 16384 + h * 8192 + (l * 512 + w64) * 8));
        }
    };
    auto stageB = [&](int b, int T) {
        const int Tk = (T & 63) * 64;
#pragma unroll
        for (int l = 0; l < 2; ++l) {
            const int idx = l * 512 + w64 + lane;
            const int r   = idx >> 3;
            const int bc  = (idx & 7) ^ (r & 7);
            GLOAD_LDS16(wt + (size_t)(n0 + r) * Kdim + Tk + bc * 8,
                        Bs + (b * 8192 + (l * 512 + w64) * 8));
        }
    };
    auto lda = [&](int b, int mt) -> bf16x8 {
        const int r = mt * 16 + l16;
        return *(const bf16x8*)(As + b * 16384 + wm * 8192 + r * 64 +
                                ((wk * 4 + quad) ^ (l16 & 7)) * 8);
    };
    auto ldb = [&](int b, int nt) -> bf16x8 {
        const int r = wn * 64 + nt * 16 + l16;
        return *(const bf16x8*)(Bs + b * 8192 + r * 64 +
                                ((wk * 4 + quad) ^ (l16 & 7)) * 8);
    };

    floatx4 acc[8][4];
#pragma unroll
    for (int i = 0; i < 8; ++i)
#pragma unroll
        for (int j = 0; j < 4; ++j)
            acc[i][j] = (floatx4){0.f, 0.f, 0.f, 0.f};

    // prologue: tiles 0,1 staged (12 loads); vmcnt(6) -> tile 0 landed
    stageA(0, 0, 0); stageA(0, 0, 1); stageB(0, 0);
    stageA(1, 1, 0); stageA(1, 1, 1); stageB(1, 1);
    VMCNT6(); BAR();

    bf16x8 av[4], bb[4];

#define MFMA16(G)                                                              \
    PRIO1();                                                                   \
    _Pragma("unroll") for (int mt = 0; mt < 4; ++mt)                           \
        _Pragma("unroll") for (int nt = 0; nt < 4; ++nt)                       \
            acc[(G)*4 + mt][nt] = MFMA(av[mt], bb[nt], acc[(G)*4 + mt][nt]);   \
    PRIO0();

    int rb = 0;                        // read buf for tile kt
    for (int kt = 0; kt < 64; ++kt) {
        int sb = rb + 2; if (sb >= 3) sb -= 3;   // stage buf for tile kt+2

        // ---- phase A: stage A(kt+2); read+MFMA frags 0-3 of tile kt ----
        stageA(sb, kt + 2, 0); stageA(sb, kt + 2, 1);
        bb[0] = ldb(rb, 0); bb[1] = ldb(rb, 1); bb[2] = ldb(rb, 2); bb[3] = ldb(rb, 3);
        av[0] = lda(rb, 0); av[1] = lda(rb, 1); av[2] = lda(rb, 2); av[3] = lda(rb, 3);
        BAR(); LGKM0();
        MFMA16(0);
        BAR();

        // ---- phase B: stage B(kt+2); read+MFMA frags 4-7 (bb reused) ----
        stageB(sb, kt + 2);
        av[0] = lda(rb, 4); av[1] = lda(rb, 5); av[2] = lda(rb, 6); av[3] = lda(rb, 7);
        VMCNT6();                      // tile kt+1 landed (leaves kt+2's 6)
        BAR(); LGKM0();
        MFMA16(1);
        BAR();

        rb += 1; if (rb >= 3) rb -= 3;
    }
#undef MFMA16

    // drain tail garbage stages (they target bufs 1,2 which overlap the
    // exchange buffer) before reusing LDS
    VMCNT0(); BAR();

    // ---- cross-k reduction: partner wave = w^1 (same wm,wn, other wk).
    // wk0 keeps m-frags 0-3 (sends 4-7); wk1 keeps 4-7 (sends 0-3).
    // Static acc indices (rule #20); barriers uniform outside branches.
    {
        float* exf = (float*)As;           // 8 waves * 2048 floats = 64 KiB
        const int pw = w ^ 1;
#pragma unroll
        for (int c = 0; c < 2; ++c) {
            if (wk == 0) {
#pragma unroll
                for (int q = 0; q < 2; ++q)
#pragma unroll
                    for (int nt = 0; nt < 4; ++nt)
                        *(floatx4*)(exf + w * 2048 + ((q * 4 + nt) * 64 + lane) * 4) =
                            acc[4 + c * 2 + q][nt];
            } else {
#pragma unroll
                for (int q = 0; q < 2; ++q)
#pragma unroll
                    for (int nt = 0; nt < 4; ++nt)
                        *(floatx4*)(exf + w * 2048 + ((q * 4 + nt) * 64 + lane) * 4) =
                            acc[c * 2 + q][nt];
            }
            __syncthreads();
            if (wk == 0) {
#pragma unroll
                for (int q = 0; q < 2; ++q)
#pragma unroll
                    for (int nt = 0; nt < 4; ++nt)
                        acc[c * 2 + q][nt] += *(const floatx4*)(exf + pw * 2048 +
                                                ((q * 4 + nt) * 64 + lane) * 4);
            } else {
#pragma unroll
                for (int q = 0; q < 2; ++q)
#pragma unroll
                    for (int nt = 0; nt < 4; ++nt)
                        acc[4 + c * 2 + q][nt] += *(const floatx4*)(exf + pw * 2048 +
                                                ((q * 4 + nt) * 64 + lane) * 4);
            }
            __syncthreads();
        }
    }

    // ---- store: wk0 stores m-frags 0-3, wk1 stores 4-7 (static indices) ----
    if (wk == 0) {
#pragma unroll
        for (int nt = 0; nt < 4; ++nt) {
            const int col = n0 + wn * 64 + nt * 16 + l16;
            const float bv = bias[col];
#pragma unroll
            for (int q = 0; q < 4; ++q)
#pragma unroll
                for (int r = 0; r < 4; ++r) {
                    const int row = m0 + wm * 128 + q * 16 + quad * 4 + r;
                    out[(size_t)row * Ndim + col] = acc[q][nt][r] + bv;
                }
        }
    } else {
#pragma unroll
        for (int nt = 0; nt < 4; ++nt) {
            const int col = n0 + wn * 64 + nt * 16 + l16;
            const float bv = bias[col];
#pragma unroll
            for (int q = 0; q < 4; ++q)
#pragma unroll
                for (int r = 0; r < 4; ++r) {
                    const int row = m0 + wm * 128 + (4 + q) * 16 + quad * 4 + r;
                    out[(size_t)row * Ndim + col] = acc[4 + q][nt][r] + bv;
                }
        }
    }
}

// ---------------------------------------------------------------------------
// Fused fallback (round-0 verified kernel) for small workspace.
// ---------------------------------------------------------------------------
template <bool PRE>
__global__ __launch_bounds__(256, 3)
void qgemm_kernel(const float* __restrict__ x,
                  const bf16_t* __restrict__ xb,
                  const uint* __restrict__ qweight,
                  const uint* __restrict__ qzeros,
                  const float* __restrict__ scales,
                  const float* __restrict__ bias,
                  float* __restrict__ out)
{
    __shared__ bf16_t As[BM * SA];
    __shared__ bf16_t Bs[BN * SB];
    __shared__ uint   qbuf[16 * SQ];

    const int t  = threadIdx.x;
    const int m0 = blockIdx.y * BM;
    const int n0 = blockIdx.x * BN;
    const int c0 = n0 >> 3;

    const int wave = t >> 6;
    const int lane = t & 63;
    const int quad = lane >> 4;
    const int l16  = lane & 15;
    const int mw = (wave >> 1) * 64;
    const int nw = (wave & 1) * 64;

    floatx4 acc[4][4];
#pragma unroll
    for (int i = 0; i < 4; ++i)
#pragma unroll
        for (int j = 0; j < 4; ++j)
            acc[i][j] = (floatx4){0.f, 0.f, 0.f, 0.f};

    const int am = t >> 3;
    const int ao = t & 7;
    const int qk  = t >> 2;
    const int qc4 = (t & 3) * 4;
    const int nloc  = t & 127;
    const int khalf = t >> 7;
    const int cc    = nloc >> 3;
    const int jsh   = (nloc & 7) * 4;

    for (int kt = 0; kt < Kdim / BK; ++kt) {
        const int k0 = kt * BK;
        const int g  = k0 >> 7;

#pragma unroll
        for (int p = 0; p < 4; ++p) {
            const int m = p * 32 + am;
            if (PRE) {
                const bf16x8 v = *(const bf16x8*)(xb + (size_t)(m0 + m) * Kdim + k0 + ao * 8);
                *(bf16x8*)&As[m * SA + ao * 8] = v;
            } else {
                const float* src = x + (size_t)(m0 + m) * Kdim + k0 + ao * 8;
                const float4 a = *(const float4*)src;
                const float4 b = *(const float4*)(src + 4);
                bf16x8 v;
                v[0] = (bf16_t)a.x; v[1] = (bf16_t)a.y; v[2] = (bf16_t)a.z; v[3] = (bf16_t)a.w;
                v[4] = (bf16_t)b.x; v[5] = (bf16_t)b.y; v[6] = (bf16_t)b.z; v[7] = (bf16_t)b.w;
                *(bf16x8*)&As[m * SA + ao * 8] = v;
            }
        }
        {
            const uint4 w4 = *(const uint4*)(qweight + (size_t)(k0 + qk) * NPK + c0 + qc4);
            qbuf[(qc4 + 0) * SQ + qk] = w4.x;
            qbuf[(qc4 + 1) * SQ + qk] = w4.y;
            qbuf[(qc4 + 2) * SQ + qk] = w4.z;
            qbuf[(qc4 + 3) * SQ + qk] = w4.w;
        }
        __syncthreads();

        {
            const uint  zw = qzeros[(size_t)g * NPK + c0 + cc];
            const float s  = scales[(size_t)g * Ndim + n0 + nloc];
            const float zs = (float)((zw >> jsh) & 15u) * s;
            const uint* qrow = &qbuf[cc * SQ + khalf * 32];
#pragma unroll
            for (int j = 0; j < 4; ++j) {
                const uint4 qa = *(const uint4*)(qrow + j * 8);
                const uint4 qb = *(const uint4*)(qrow + j * 8 + 4);
                bf16x8 v;
                v[0] = (bf16_t)((float)((qa.x >> jsh) & 15u) * s - zs);
                v[1] = (bf16_t)((float)((qa.y >> jsh) & 15u) * s - zs);
                v[2] = (bf16_t)((float)((qa.z >> jsh) & 15u) * s - zs);
                v[3] = (bf16_t)((float)((qa.w >> jsh) & 15u) * s - zs);
                v[4] = (bf16_t)((float)((qb.x >> jsh) & 15u) * s - zs);
                v[5] = (bf16_t)((float)((qb.y >> jsh) & 15u) * s - zs);
                v[6] = (bf16_t)((float)((qb.z >> jsh) & 15u) * s - zs);
                v[7] = (bf16_t)((float)((qb.w >> jsh) & 15u) * s - zs);
                *(bf16x8*)&Bs[nloc * SB + khalf * 32 + j * 8] = v;
            }
        }
        __syncthreads();

#pragma unroll
        for (int s = 0; s < 2; ++s) {
            bf16x8 fa[4], fb[4];
#pragma unroll
            for (int mt = 0; mt < 4; ++mt)
                fa[mt] = *(const bf16x8*)&As[(mw + mt * 16 + l16) * SA + s * 32 + quad * 8];
#pragma unroll
            for (int nt = 0; nt < 4; ++nt)
                fb[nt] = *(const bf16x8*)&Bs[(nw + nt * 16 + l16) * SB + s * 32 + quad * 8];
#pragma unroll
            for (int mt = 0; mt < 4; ++mt)
#pragma unroll
                for (int nt = 0; nt < 4; ++nt)
                    acc[mt][nt] = MFMA(fa[mt], fb[nt], acc[mt][nt]);
        }
        __syncthreads();
    }

#pragma unroll
    for (int nt = 0; nt < 4; ++nt) {
        const int col = n0 + nw + nt * 16 + l16;
        const float b = bias[col];
#pragma unroll
        for (int mt = 0; mt < 4; ++mt) {
#pragma unroll
            for (int r = 0; r < 4; ++r) {
                const int row = m0 + mw + mt * 16 + quad * 4 + r;
                out[(size_t)row * Ndim + col] = acc[mt][nt][r] + b;
            }
        }
    }
}

extern "C" void kernel_launch(void* const* d_in, const int* in_sizes, int n_in,
                              void* d_out, int out_size, void* d_ws, size_t ws_size,
                              hipStream_t stream)
{
    const float* x        = (const float*)d_in[0];
    const uint*  qweight  = (const uint*)d_in[1];
    const uint*  qzeros   = (const uint*)d_in[2];
    const float* scales   = (const float*)d_in[3];
    const float* bias     = (const float*)d_in[4];
    float*       out      = (float*)d_out;

    const size_t wb_bytes = (size_t)Kdim * Ndim * sizeof(bf16_t);   // 90.2 MB
    const size_t xb_bytes = (size_t)Mdim * Kdim * sizeof(bf16_t);   // 16.8 MB

    if (ws_size >= wb_bytes + xb_bytes) {
        // pre-dequant (+fused xcast) + 3-deep phased GEMM
        bf16_t* wt   = (bf16_t*)d_ws;
        bf16_t* xbuf = (bf16_t*)((char*)d_ws + wb_bytes);
        wprep_kernel<<<dim3(Ndim / 128, Kdim / 64), 256, 0, stream>>>(qweight, qzeros, scales, wt, x, xbuf);
        gemm8_kernel<<<dim3(86, 8), dim3(512), 0, stream>>>(xbuf, wt, bias, out);
    } else {
        // fused fallback
        bf16_t* xbuf = (bf16_t*)d_ws;
        dim3 ggrid(Ndim / BN, Mdim / BM);
        if (ws_size >= xb_bytes) {
            xcast_kernel<<<(Mdim * Kdim) / (256 * 8), 256, 0, stream>>>(x, xbuf);
            qgemm_kernel<true><<<ggrid, dim3(256), 0, stream>>>(x, xbuf, qweight, qzeros, scales, bias, out);
        } else {
            qgemm_kernel<false><<<ggrid, dim3(256), 0, stream>>>(x, xbuf, qweight, qzeros, scales, bias, out);
        }
    }
}

// Round 8
// 350.376 us; speedup vs baseline: 1.4639x; 1.4639x over previous
//
#include <hip/hip_runtime.h>

typedef __bf16 bf16_t;
typedef bf16_t bf16x8 __attribute__((ext_vector_type(8)));
typedef float  floatx4 __attribute__((ext_vector_type(4)));
typedef unsigned int uint;

constexpr int Mdim = 2048;
constexpr int Kdim = 4096;
constexpr int Ndim = 11008;
constexpr int NPK  = Ndim / 8;     // 1376 packed words per k-row
constexpr int SQ   = 68;           // qbuf stride (words)
// fused-fallback tile params
constexpr int BM = 128, BN = 128, BK = 64;
constexpr int SA = 72, SB = 72;

#define GLOAD_LDS16(g, l) \
    __builtin_amdgcn_global_load_lds((const __attribute__((address_space(1))) void*)(g), \
                                     (__attribute__((address_space(3))) void*)(l), 16, 0, 0)
#define MFMA(a, b, c) __builtin_amdgcn_mfma_f32_16x16x32_bf16((a), (b), (c), 0, 0, 0)
#define PRIO1()  __builtin_amdgcn_s_setprio(1)
#define PRIO0()  __builtin_amdgcn_s_setprio(0)

__global__ void xcast_kernel(const float* __restrict__ x, bf16_t* __restrict__ xb)
{
    const int i = (blockIdx.x * 256 + threadIdx.x) * 8;
    const float4 a = *(const float4*)(x + i);
    const float4 b = *(const float4*)(x + i + 4);
    bf16x8 v;
    v[0] = (bf16_t)a.x; v[1] = (bf16_t)a.y; v[2] = (bf16_t)a.z; v[3] = (bf16_t)a.w;
    v[4] = (bf16_t)b.x; v[5] = (bf16_t)b.y; v[6] = (bf16_t)b.z; v[7] = (bf16_t)b.w;
    *(bf16x8*)(xb + i) = v;
}

// ---------------------------------------------------------------------------
// Fused prep: W dequant (qweight [k][c] -> wt [n][k] bf16) + xcast slice.
// ---------------------------------------------------------------------------
__global__ __launch_bounds__(256, 4)
void wprep_kernel(const uint* __restrict__ qweight, const uint* __restrict__ qzeros,
                  const float* __restrict__ scales, bf16_t* __restrict__ wt,
                  const float* __restrict__ x, bf16_t* __restrict__ xb)
{
    __shared__ uint qbuf[16 * SQ];
    const int t    = threadIdx.x;
    const int n0   = blockIdx.x * 128;
    const int k0   = blockIdx.y * 64;
    const int c0   = n0 >> 3;
    const int g    = k0 >> 7;
    const int flat = blockIdx.y * 86 + blockIdx.x;

    // --- xcast slice: issue load early ---
    const int xi = flat * 256 + t;                 // vec8 index
    const bool xdo = xi < (Mdim * Kdim) / 8;
    float4 xa, xb4;
    if (xdo) {
        xa  = *(const float4*)(x + xi * 8);
        xb4 = *(const float4*)(x + xi * 8 + 4);
    }

    // --- wdeq stage: 64k x 16c packed words, transposed to qbuf[c][k] ---
    const int qk  = t >> 2;
    const int qc4 = (t & 3) * 4;
    const uint4 w4 = *(const uint4*)(qweight + (size_t)(k0 + qk) * NPK + c0 + qc4);
    qbuf[(qc4 + 0) * SQ + qk] = w4.x;
    qbuf[(qc4 + 1) * SQ + qk] = w4.y;
    qbuf[(qc4 + 2) * SQ + qk] = w4.z;
    qbuf[(qc4 + 3) * SQ + qk] = w4.w;
    __syncthreads();

    const int kcol = t & 7;            // k-word block
    const int nr   = t >> 3;           // 0..31
    const int jsh  = (nr & 7) * 4;     // invariant across j (row += 32)
#pragma unroll
    for (int j = 0; j < 4; ++j) {
        const int row = nr + j * 32;          // 0..127
        const int cc  = row >> 3;             // 0..15
        const uint  zw = qzeros[(size_t)g * NPK + c0 + cc];
        const float s  = scales[(size_t)g * Ndim + n0 + row];
        const float zs = (float)((zw >> jsh) & 15u) * s;
        const uint* qrow = &qbuf[cc * SQ + kcol * 8];
        const uint4 qa = *(const uint4*)(qrow);
        const uint4 qb = *(const uint4*)(qrow + 4);
        bf16x8 v;
        v[0] = (bf16_t)((float)((qa.x >> jsh) & 15u) * s - zs);
        v[1] = (bf16_t)((float)((qa.y >> jsh) & 15u) * s - zs);
        v[2] = (bf16_t)((float)((qa.z >> jsh) & 15u) * s - zs);
        v[3] = (bf16_t)((float)((qa.w >> jsh) & 15u) * s - zs);
        v[4] = (bf16_t)((float)((qb.x >> jsh) & 15u) * s - zs);
        v[5] = (bf16_t)((float)((qb.y >> jsh) & 15u) * s - zs);
        v[6] = (bf16_t)((float)((qb.z >> jsh) & 15u) * s - zs);
        v[7] = (bf16_t)((float)((qb.w >> jsh) & 15u) * s - zs);
        *(bf16x8*)(wt + (size_t)(n0 + row) * Kdim + k0 + kcol * 8) = v;
    }

    // --- xcast store ---
    if (xdo) {
        bf16x8 v;
        v[0] = (bf16_t)xa.x; v[1] = (bf16_t)xa.y; v[2] = (bf16_t)xa.z; v[3] = (bf16_t)xa.w;
        v[4] = (bf16_t)xb4.x; v[5] = (bf16_t)xb4.y; v[6] = (bf16_t)xb4.z; v[7] = (bf16_t)xb4.w;
        *(bf16x8*)(xb + xi * 8) = v;
    }
}

// ---------------------------------------------------------------------------
// m97-structure GEMM at 256x128, occupancy-first.
// 512 threads = 8 waves as 4M x 2N, wave tile 64x64, acc[4][4] (64 acc regs)
// -> ~124 total regs/wave -> 16 waves/CU = 2 blocks/CU (vs 1 for k-split).
// Single-buffered LDS: As 32 KB + Bs 16 KB = 48 KB (2 blocks fit).
// Loop = m97 2-barrier: stage(kt) -> __syncthreads (compiler emits full
// vmcnt/lgkm drain) -> ds_read+MFMA -> __syncthreads. The drain stall is
// hidden by the co-resident block (m114 implicit overlap) instead of by
// explicit scheduling (which failed rounds 5/7).
// Swizzle: 16B-chunk column  c_lds = c_glob ^ (row & 7), both sides.
// ---------------------------------------------------------------------------
__global__ __launch_bounds__(512, 4)
void gemm9_kernel(const bf16_t* __restrict__ xb, const bf16_t* __restrict__ wt,
                  const float* __restrict__ bias, float* __restrict__ out)
{
    __shared__ bf16_t As[256 * 64];    // 32 KB  [256][64]
    __shared__ bf16_t Bs[128 * 64];    // 16 KB  [128][64]

    const int t    = threadIdx.x;
    const int w    = t >> 6;
    const int lane = t & 63;
    const int quad = lane >> 4;
    const int l16  = lane & 15;
    const int wm   = w >> 1;           // 0..3  (m quarter, 64 rows)
    const int wn   = w & 1;            // 0..1  (n half, 64 cols)
    const int w64  = w * 64;

    // T1: XCD-aware remap (688 = 8*86, bijective).
    const int flat = blockIdx.y * 86 + blockIdx.x;
    const int nf   = (flat & 7) * 86 + (flat >> 3);
    const int m0   = (nf / 86) * 256;
    const int n0   = (nf % 86) * 128;

    auto stageA = [&](int T, int h) {
#pragma unroll
        for (int l = 0; l < 2; ++l) {
            const int idx = l * 512 + w64 + lane;
            const int r   = idx >> 3;              // 0..127
            const int bc  = (idx & 7) ^ (r & 7);
            GLOAD_LDS16(xb + (size_t)(m0 + h * 128 + r) * Kdim + T * 64 + bc * 8,
                        As + h * 8192 + (l * 512 + w64) * 8);
        }
    };
    auto stageB = [&](int T) {
#pragma unroll
        for (int l = 0; l < 2; ++l) {
            const int idx = l * 512 + w64 + lane;
            const int r   = idx >> 3;
            const int bc  = (idx & 7) ^ (r & 7);
            GLOAD_LDS16(wt + (size_t)(n0 + r) * Kdim + T * 64 + bc * 8,
                        Bs + (l * 512 + w64) * 8);
        }
    };
    auto lda = [&](int mt, int s) -> bf16x8 {
        const int r = wm * 64 + mt * 16 + l16;     // 0..255
        return *(const bf16x8*)(As + r * 64 + ((s * 4 + quad) ^ (l16 & 7)) * 8);
    };
    auto ldb = [&](int nt, int s) -> bf16x8 {
        const int r = wn * 64 + nt * 16 + l16;     // 0..127
        return *(const bf16x8*)(Bs + r * 64 + ((s * 4 + quad) ^ (l16 & 7)) * 8);
    };

    floatx4 acc[4][4];
#pragma unroll
    for (int i = 0; i < 4; ++i)
#pragma unroll
        for (int j = 0; j < 4; ++j)
            acc[i][j] = (floatx4){0.f, 0.f, 0.f, 0.f};

    for (int kt = 0; kt < 64; ++kt) {
        // stage tile kt (6 x global_load_lds per thread: A 4, B 2)
        stageA(kt, 0); stageA(kt, 1); stageB(kt);
        __syncthreads();               // full vmcnt/lgkm drain (compiler)

#pragma unroll
        for (int s = 0; s < 2; ++s) {
            bf16x8 fa[4], fb[4];
#pragma unroll
            for (int mt = 0; mt < 4; ++mt) fa[mt] = lda(mt, s);
#pragma unroll
            for (int nt = 0; nt < 4; ++nt) fb[nt] = ldb(nt, s);
            PRIO1();
#pragma unroll
            for (int mt = 0; mt < 4; ++mt)
#pragma unroll
                for (int nt = 0; nt < 4; ++nt)
                    acc[mt][nt] = MFMA(fa[mt], fb[nt], acc[mt][nt]);
            PRIO0();
        }
        __syncthreads();               // WAR guard before next stage
    }

    // ---- epilogue: row = quad*4+r, col = l16 per 16x16 tile (verified) ----
#pragma unroll
    for (int nt = 0; nt < 4; ++nt) {
        const int col = n0 + wn * 64 + nt * 16 + l16;
        const float bv = bias[col];
#pragma unroll
        for (int mt = 0; mt < 4; ++mt) {
#pragma unroll
            for (int r = 0; r < 4; ++r) {
                const int row = m0 + wm * 64 + mt * 16 + quad * 4 + r;
                out[(size_t)row * Ndim + col] = acc[mt][nt][r] + bv;
            }
        }
    }
}

// ---------------------------------------------------------------------------
// Fused fallback (round-0 verified kernel) for small workspace.
// ---------------------------------------------------------------------------
template <bool PRE>
__global__ __launch_bounds__(256, 3)
void qgemm_kernel(const float* __restrict__ x,
                  const bf16_t* __restrict__ xb,
                  const uint* __restrict__ qweight,
                  const uint* __restrict__ qzeros,
                  const float* __restrict__ scales,
                  const float* __restrict__ bias,
                  float* __restrict__ out)
{
    __shared__ bf16_t As[BM * SA];
    __shared__ bf16_t Bs[BN * SB];
    __shared__ uint   qbuf[16 * SQ];

    const int t  = threadIdx.x;
    const int m0 = blockIdx.y * BM;
    const int n0 = blockIdx.x * BN;
    const int c0 = n0 >> 3;

    const int wave = t >> 6;
    const int lane = t & 63;
    const int quad = lane >> 4;
    const int l16  = lane & 15;
    const int mw = (wave >> 1) * 64;
    const int nw = (wave & 1) * 64;

    floatx4 acc[4][4];
#pragma unroll
    for (int i = 0; i < 4; ++i)
#pragma unroll
        for (int j = 0; j < 4; ++j)
            acc[i][j] = (floatx4){0.f, 0.f, 0.f, 0.f};

    const int am = t >> 3;
    const int ao = t & 7;
    const int qk  = t >> 2;
    const int qc4 = (t & 3) * 4;
    const int nloc  = t & 127;
    const int khalf = t >> 7;
    const int cc    = nloc >> 3;
    const int jsh   = (nloc & 7) * 4;

    for (int kt = 0; kt < Kdim / BK; ++kt) {
        const int k0 = kt * BK;
        const int g  = k0 >> 7;

#pragma unroll
        for (int p = 0; p < 4; ++p) {
            const int m = p * 32 + am;
            if (PRE) {
                const bf16x8 v = *(const bf16x8*)(xb + (size_t)(m0 + m) * Kdim + k0 + ao * 8);
                *(bf16x8*)&As[m * SA + ao * 8] = v;
            } else {
                const float* src = x + (size_t)(m0 + m) * Kdim + k0 + ao * 8;
                const float4 a = *(const float4*)src;
                const float4 b = *(const float4*)(src + 4);
                bf16x8 v;
                v[0] = (bf16_t)a.x; v[1] = (bf16_t)a.y; v[2] = (bf16_t)a.z; v[3] = (bf16_t)a.w;
                v[4] = (bf16_t)b.x; v[5] = (bf16_t)b.y; v[6] = (bf16_t)b.z; v[7] = (bf16_t)b.w;
                *(bf16x8*)&As[m * SA + ao * 8] = v;
            }
        }
        {
            const uint4 w4 = *(const uint4*)(qweight + (size_t)(k0 + qk) * NPK + c0 + qc4);
            qbuf[(qc4 + 0) * SQ + qk] = w4.x;
            qbuf[(qc4 + 1) * SQ + qk] = w4.y;
            qbuf[(qc4 + 2) * SQ + qk] = w4.z;
            qbuf[(qc4 + 3) * SQ + qk] = w4.w;
        }
        __syncthreads();

        {
            const uint  zw = qzeros[(size_t)g * NPK + c0 + cc];
            const float s  = scales[(size_t)g * Ndim + n0 + nloc];
            const float zs = (float)((zw >> jsh) & 15u) * s;
            const uint* qrow = &qbuf[cc * SQ + khalf * 32];
#pragma unroll
            for (int j = 0; j < 4; ++j) {
                const uint4 qa = *(const uint4*)(qrow + j * 8);
                const uint4 qb = *(const uint4*)(qrow + j * 8 + 4);
                bf16x8 v;
                v[0] = (bf16_t)((float)((qa.x >> jsh) & 15u) * s - zs);
                v[1] = (bf16_t)((float)((qa.y >> jsh) & 15u) * s - zs);
                v[2] = (bf16_t)((float)((qa.z >> jsh) & 15u) * s - zs);
                v[3] = (bf16_t)((float)((qa.w >> jsh) & 15u) * s - zs);
                v[4] = (bf16_t)((float)((qb.x >> jsh) & 15u) * s - zs);
                v[5] = (bf16_t)((float)((qb.y >> jsh) & 15u) * s - zs);
                v[6] = (bf16_t)((float)((qb.z >> jsh) & 15u) * s - zs);
                v[7] = (bf16_t)((float)((qb.w >> jsh) & 15u) * s - zs);
                *(bf16x8*)&Bs[nloc * SB + khalf * 32 + j * 8] = v;
            }
        }
        __syncthreads();

#pragma unroll
        for (int s = 0; s < 2; ++s) {
            bf16x8 fa[4], fb[4];
#pragma unroll
            for (int mt = 0; mt < 4; ++mt)
                fa[mt] = *(const bf16x8*)&As[(mw + mt * 16 + l16) * SA + s * 32 + quad * 8];
#pragma unroll
            for (int nt = 0; nt < 4; ++nt)
                fb[nt] = *(const bf16x8*)&Bs[(nw + nt * 16 + l16) * SB + s * 32 + quad * 8];
#pragma unroll
            for (int mt = 0; mt < 4; ++mt)
#pragma unroll
                for (int nt = 0; nt < 4; ++nt)
                    acc[mt][nt] = MFMA(fa[mt], fb[nt], acc[mt][nt]);
        }
        __syncthreads();
    }

#pragma unroll
    for (int nt = 0; nt < 4; ++nt) {
        const int col = n0 + nw + nt * 16 + l16;
        const float b = bias[col];
#pragma unroll
        for (int mt = 0; mt < 4; ++mt) {
#pragma unroll
            for (int r = 0; r < 4; ++r) {
                const int row = m0 + mw + mt * 16 + quad * 4 + r;
                out[(size_t)row * Ndim + col] = acc[mt][nt][r] + b;
            }
        }
    }
}

extern "C" void kernel_launch(void* const* d_in, const int* in_sizes, int n_in,
                              void* d_out, int out_size, void* d_ws, size_t ws_size,
                              hipStream_t stream)
{
    const float* x        = (const float*)d_in[0];
    const uint*  qweight  = (const uint*)d_in[1];
    const uint*  qzeros   = (const uint*)d_in[2];
    const float* scales   = (const float*)d_in[3];
    const float* bias     = (const float*)d_in[4];
    float*       out      = (float*)d_out;

    const size_t wb_bytes = (size_t)Kdim * Ndim * sizeof(bf16_t);   // 90.2 MB
    const size_t xb_bytes = (size_t)Mdim * Kdim * sizeof(bf16_t);   // 16.8 MB

    if (ws_size >= wb_bytes + xb_bytes) {
        // pre-dequant (+fused xcast) + occupancy-first m97-structure GEMM
        bf16_t* wt   = (bf16_t*)d_ws;
        bf16_t* xbuf = (bf16_t*)((char*)d_ws + wb_bytes);
        wprep_kernel<<<dim3(Ndim / 128, Kdim / 64), 256, 0, stream>>>(qweight, qzeros, scales, wt, x, xbuf);
        gemm9_kernel<<<dim3(86, 8), dim3(512), 0, stream>>>(xbuf, wt, bias, out);
    } else {
        // fused fallback
        bf16_t* xbuf = (bf16_t*)d_ws;
        dim3 ggrid(Ndim / BN, Mdim / BM);
        if (ws_size >= xb_bytes) {
            xcast_kernel<<<(Mdim * Kdim) / (256 * 8), 256, 0, stream>>>(x, xbuf);
            qgemm_kernel<true><<<ggrid, dim3(256), 0, stream>>>(x, xbuf, qweight, qzeros, scales, bias, out);
        } else {
            qgemm_kernel<false><<<ggrid, dim3(256), 0, stream>>>(x, xbuf, qweight, qzeros, scales, bias, out);
        }
    }
}